// Round 3
// baseline (3331.209 us; speedup 1.0000x reference)
//
#include <hip/hip_runtime.h>
#include <hip/hip_bf16.h>

// ---------------------------------------------------------------------------
// TemporalAttention on MI355X (gfx950).
// b=4, n=8, h=32, w=32 (2*16 concat), c(tokens)=1024, d_emb=8192, H=8, Dk=Dv=256
// INPUTS: float32 (per reference). OUTPUT: float32. Internal: bf16 MFMA, f32 acc.
//
// ws layout (peak 144 MiB + 32 B):
//   [0,   64M)  x        bf16 [4096][8192]   residual, live until out-proj
//   [64,  80M)  q / z2   bf16 [4096][2048]
//   [80,  96M)  k        bf16 [4096][2048]
//   [96, 112M)  v        bf16 [4096][2048]
//   [112,144M)  sc       f32  [8][1024][1024]  per-batch scores (sequential b)
//   [80, 144M)  zo       bf16 [4096][8192]   overlays dead k/v/sc after attn
//   [144M,+32B) stats    f32  [4][2]
// ---------------------------------------------------------------------------

typedef __attribute__((ext_vector_type(4))) float f32x4;
typedef __attribute__((ext_vector_type(8))) __bf16 bf16x8;
typedef __attribute__((ext_vector_type(8))) unsigned short ushort8;
typedef __attribute__((ext_vector_type(4))) unsigned short ushort4v;
typedef __attribute__((ext_vector_type(4))) unsigned int uint4v;

static __device__ __forceinline__ float bf2f(unsigned short u) {
    unsigned int x = ((unsigned int)u) << 16;
    return __builtin_bit_cast(float, x);
}
static __device__ __forceinline__ unsigned short f2bf(float f) {
    unsigned int x = __builtin_bit_cast(unsigned int, f);
    unsigned int lsb = (x >> 16) & 1u;
    x += 0x7fffu + lsb;                 // round-to-nearest-even
    return (unsigned short)(x >> 16);
}

// ---------------------------------------------------------------------------
// Kernel 1: gather/concat + 'b n h w c -> b c (n h w)' transpose + 0.001*PE
// f32 in, bf16 out.
// ---------------------------------------------------------------------------
__global__ __launch_bounds__(256) void build_x_kernel(
    const float* __restrict__ ref_img,
    const float* __restrict__ hdmap,
    unsigned short* __restrict__ x)
{
    __shared__ float tile[32][72];            // [w][t], padded (288B rows, 16B-mult)
    int slab = blockIdx.y;                    // b*256 + n*32 + h
    int b = slab >> 8;
    int n = (slab >> 5) & 7;
    int h = slab & 31;
    int t0 = blockIdx.x * 64;
    int tid = threadIdx.x;

    {   // phase 1: coalesced read along t
        int w  = tid >> 3;      // 0..31
        int tg = tid & 7;       // 0..7 -> 8 f32 each
        const float* src = (w < 16)
            ? ref_img + ((size_t)(((b * 8 + n) * 32 + h) * 16 + w) * 1024 + t0 + tg * 8)
            : hdmap   + ((size_t)(((b * 8 + n) * 32 + h) * 16 + (w - 16)) * 1024 + t0 + tg * 8);
        *(f32x4*)&tile[w][tg * 8]     = *(const f32x4*)src;
        *(f32x4*)&tile[w][tg * 8 + 4] = *(const f32x4*)(src + 4);
    }
    __syncthreads();
    {   // phase 2: write x[t][f], f = n*1024 + h*32 + w; add 0.001*PE(t,f)
        int tau = tid >> 2;     // 0..63
        int wg  = tid & 3;      // 0..3
        int t = t0 + tau;
        const float L = 13.287712379549449f;  // log2(10000)
        ushort8 o;
        #pragma unroll
        for (int e = 0; e < 8; ++e) {
            int w = wg * 8 + e;
            int f = n * 1024 + h * 32 + w;
            int j = f >> 1;
            float ex = ((f & 1) ? (4.0f * (float)j + 2.0f) : (4.0f * (float)j)) * (1.0f / 8192.0f);
            float freq = exp2f(-ex * L);
            float arg = (float)t * freq;
            float pe = (f & 1) ? cosf(arg) : sinf(arg);
            o[e] = f2bf(tile[w][tau] + 0.001f * pe);
        }
        unsigned short* dst = x + ((size_t)(b * 1024 + t)) * 8192 + n * 1024 + h * 32 + wg * 8;
        *(ushort8*)dst = o;
    }
}

// ---------------------------------------------------------------------------
// Templated MFMA GEMM (128x128 tile, BK=32, 4 waves, 16x16x32 bf16 mfma)
//   A_F32 : A is f32 (converted to bf16 in staging)
//   B_F32 : B is f32 (NN only), converted in staging
//   B_TRANS: B stored [N,K] (bf16 only)
//   OUT_F32, RESID (bf16 resid)
// ---------------------------------------------------------------------------
template<int A_F32, int B_F32, int B_TRANS, int OUT_F32, int RESID>
__global__ __launch_bounds__(256) void gemm_kernel(
    const void* __restrict__ Ap, const void* __restrict__ Bp, void* __restrict__ Cp,
    const unsigned short* __restrict__ resid,
    int M, int N, int K, int lda, int ldb, int ldc,
    int bdiv, long sA1, long sA2, long sB1, long sB2, long sC1, long sC2,
    float alpha)
{
    __shared__ unsigned short As[128][40];    // [m][k]
    __shared__ unsigned short Bs[128][40];    // [n][k]

    int z = blockIdx.z;
    long aoff = (long)(z / bdiv) * sA1 + (long)(z % bdiv) * sA2;
    long boff = (long)(z / bdiv) * sB1 + (long)(z % bdiv) * sB2;
    long coff = (long)(z / bdiv) * sC1 + (long)(z % bdiv) * sC2;

    int bm = blockIdx.y * 128, bn = blockIdx.x * 128;
    int tid = threadIdx.x;
    int lane = tid & 63, wave = tid >> 6;
    int wm = (wave >> 1) * 64, wn = (wave & 1) * 64;
    int l15 = lane & 15, quad = lane >> 4;

    const unsigned short* Ab = (const unsigned short*)Ap;
    const float*          Af = (const float*)Ap;
    const unsigned short* Bb = (const unsigned short*)Bp;
    const float*          Bf = (const float*)Bp;

    f32x4 acc[4][4] = {};

    for (int k0 = 0; k0 < K; k0 += 32) {
        // ---- stage A tile [128 m][32 k] ----
        #pragma unroll
        for (int i = 0; i < 2; ++i) {
            int idx = tid + i * 256;          // 0..511 chunks of 8
            int row = idx >> 2;
            int kg  = (idx & 3) * 8;
            if (!A_F32) {
                *(uint4v*)&As[row][kg] =
                    *(const uint4v*)(Ab + aoff + (long)(bm + row) * lda + k0 + kg);
            } else {
                const float* p = Af + aoff + (long)(bm + row) * lda + k0 + kg;
                f32x4 v0 = *(const f32x4*)p;
                f32x4 v1 = *(const f32x4*)(p + 4);
                ushort8 s;
                s[0] = f2bf(v0[0]); s[1] = f2bf(v0[1]); s[2] = f2bf(v0[2]); s[3] = f2bf(v0[3]);
                s[4] = f2bf(v1[0]); s[5] = f2bf(v1[1]); s[6] = f2bf(v1[2]); s[7] = f2bf(v1[3]);
                *(ushort8*)&As[row][kg] = s;
            }
        }
        // ---- stage B tile -> Bs[n][k] ----
        #pragma unroll
        for (int i = 0; i < 2; ++i) {
            int idx = tid + i * 256;
            if (B_TRANS) {                     // bf16 B[N,K]
                int row = idx >> 2;
                int kg  = (idx & 3) * 8;
                *(uint4v*)&Bs[row][kg] =
                    *(const uint4v*)(Bb + boff + (long)(bn + row) * ldb + k0 + kg);
            } else if (!B_F32) {               // bf16 B[K,N]
                int k  = idx >> 4;             // 0..31
                int ng = (idx & 15) * 8;       // 0..120
                ushort8 v = *(const ushort8*)(Bb + boff + (long)(k0 + k) * ldb + bn + ng);
                #pragma unroll
                for (int e = 0; e < 8; ++e) Bs[ng + e][k] = v[e];
            } else {                           // f32 B[K,N]
                int k  = idx >> 4;
                int ng = (idx & 15) * 8;
                const float* p = Bf + boff + (long)(k0 + k) * ldb + bn + ng;
                f32x4 v0 = *(const f32x4*)p;
                f32x4 v1 = *(const f32x4*)(p + 4);
                Bs[ng + 0][k] = f2bf(v0[0]); Bs[ng + 1][k] = f2bf(v0[1]);
                Bs[ng + 2][k] = f2bf(v0[2]); Bs[ng + 3][k] = f2bf(v0[3]);
                Bs[ng + 4][k] = f2bf(v1[0]); Bs[ng + 5][k] = f2bf(v1[1]);
                Bs[ng + 6][k] = f2bf(v1[2]); Bs[ng + 7][k] = f2bf(v1[3]);
            }
        }
        __syncthreads();

        bf16x8 af[4], bfv[4];
        #pragma unroll
        for (int mi = 0; mi < 4; ++mi)
            af[mi] = *(const bf16x8*)&As[wm + mi * 16 + l15][quad * 8];
        #pragma unroll
        for (int ni = 0; ni < 4; ++ni)
            bfv[ni] = *(const bf16x8*)&Bs[wn + ni * 16 + l15][quad * 8];
        #pragma unroll
        for (int mi = 0; mi < 4; ++mi)
            #pragma unroll
            for (int ni = 0; ni < 4; ++ni)
                acc[mi][ni] = __builtin_amdgcn_mfma_f32_16x16x32_bf16(
                    af[mi], bfv[ni], acc[mi][ni], 0, 0, 0);
        __syncthreads();
    }

    // ---- epilogue: C/D layout col=lane&15, row=quad*4+reg ----
    #pragma unroll
    for (int mi = 0; mi < 4; ++mi) {
        #pragma unroll
        for (int ni = 0; ni < 4; ++ni) {
            #pragma unroll
            for (int r = 0; r < 4; ++r) {
                int row = bm + wm + mi * 16 + quad * 4 + r;
                int col = bn + wn + ni * 16 + l15;
                float v = acc[mi][ni][r] * alpha;
                if (RESID) v += bf2f(resid[(long)row * ldc + col]);
                long ci = coff + (long)row * ldc + col;
                if (OUT_F32) ((float*)Cp)[ci] = v;
                else         ((unsigned short*)Cp)[ci] = f2bf(v);
            }
        }
    }
}

// ---------------------------------------------------------------------------
// Row softmax, in place, f32.
// ---------------------------------------------------------------------------
__global__ __launch_bounds__(256) void softmax_kernel(float* __restrict__ s)
{
    long row = blockIdx.x;
    float* p = s + row * 1024;
    int tid = threadIdx.x;
    int lane = tid & 63, wv = tid >> 6;

    f32x4 v = *(const f32x4*)(p + tid * 4);
    float m = fmaxf(fmaxf(v[0], v[1]), fmaxf(v[2], v[3]));
    #pragma unroll
    for (int off = 32; off; off >>= 1) m = fmaxf(m, __shfl_xor(m, off, 64));
    __shared__ float redm[4];
    if (lane == 0) redm[wv] = m;
    __syncthreads();
    m = fmaxf(fmaxf(redm[0], redm[1]), fmaxf(redm[2], redm[3]));

    f32x4 e;
    e[0] = __expf(v[0] - m); e[1] = __expf(v[1] - m);
    e[2] = __expf(v[2] - m); e[3] = __expf(v[3] - m);
    float sum = e[0] + e[1] + e[2] + e[3];
    #pragma unroll
    for (int off = 32; off; off >>= 1) sum += __shfl_xor(sum, off, 64);
    __shared__ float reds[4];
    if (lane == 0) reds[wv] = sum;
    __syncthreads();
    sum = reds[0] + reds[1] + reds[2] + reds[3];

    float inv = 1.0f / sum;
    e[0] *= inv; e[1] *= inv; e[2] *= inv; e[3] *= inv;
    *(f32x4*)(p + tid * 4) = e;
}

// ---------------------------------------------------------------------------
// LayerNorm pass 1: per-batch sum/sumsq over bf16 zo [1024*8192].
// ---------------------------------------------------------------------------
__global__ __launch_bounds__(256) void ln_stats_kernel(
    const unsigned short* __restrict__ zo, float* __restrict__ stats)
{
    int b = blockIdx.y;
    const ushort8* p = (const ushort8*)(zo + (long)b * 8388608);
    float s = 0.f, sq = 0.f;
    for (int i = blockIdx.x * 256 + threadIdx.x; i < 1048576; i += 128 * 256) {
        ushort8 u = p[i];
        #pragma unroll
        for (int e = 0; e < 8; ++e) {
            float f = bf2f(u[e]);
            s += f; sq += f * f;
        }
    }
    #pragma unroll
    for (int off = 32; off; off >>= 1) {
        s += __shfl_xor(s, off, 64);
        sq += __shfl_xor(sq, off, 64);
    }
    __shared__ float rs[4], rq[4];
    int lane = threadIdx.x & 63, wv = threadIdx.x >> 6;
    if (lane == 0) { rs[wv] = s; rq[wv] = sq; }
    __syncthreads();
    if (threadIdx.x == 0) {
        atomicAdd(&stats[b * 2 + 0], rs[0] + rs[1] + rs[2] + rs[3]);
        atomicAdd(&stats[b * 2 + 1], rq[0] + rq[1] + rq[2] + rq[3]);
    }
}

// ---------------------------------------------------------------------------
// LayerNorm apply + gamma/beta (f32) + 'b (h w) (n c) -> b n c h w' permute.
// Output f32.
// ---------------------------------------------------------------------------
__global__ __launch_bounds__(256) void ln_apply_kernel(
    const unsigned short* __restrict__ zo,
    const float* __restrict__ gamma,
    const float* __restrict__ beta,
    const float* __restrict__ stats,
    float* __restrict__ out)
{
    __shared__ float tile[64][65];
    int b = blockIdx.z, t0 = blockIdx.y * 64, f0 = blockIdx.x * 64;
    float mean = stats[b * 2 + 0] * (1.0f / 8388608.0f);
    float var  = stats[b * 2 + 1] * (1.0f / 8388608.0f) - mean * mean;
    float rstd = rsqrtf(var + 1e-6f);
    int tid = threadIdx.x;

    #pragma unroll
    for (int i = 0; i < 4; ++i) {
        int rt = (tid >> 4) + i * 16;   // token-local 0..63
        int c4 = (tid & 15) * 4;        // f-local
        long zi = (long)b * 8388608 + (long)(t0 + rt) * 8192 + f0 + c4;
        ushort4v zv = *(const ushort4v*)(zo + zi);
        long gi = (long)(t0 + rt) * 8192 + f0 + c4;
        f32x4 g  = *(const f32x4*)(gamma + gi);
        f32x4 bt = *(const f32x4*)(beta + gi);
        #pragma unroll
        for (int e = 0; e < 4; ++e)
            tile[rt][c4 + e] = (bf2f(zv[e]) - mean) * rstd * g[e] + bt[e];
    }
    __syncthreads();

    int fl = tid >> 2;                  // f-local 0..63
    int tg = tid & 3;                   // token group (16 tokens each)
    int f = f0 + fl;
    int np = f >> 10, cp = f & 1023;
    long obase = ((long)((b * 8 + np) * 1024 + cp)) * 1024 + t0 + tg * 16;
    #pragma unroll
    for (int c = 0; c < 4; ++c) {
        f32x4 o;
        #pragma unroll
        for (int e = 0; e < 4; ++e) o[e] = tile[tg * 16 + c * 4 + e][fl];
        *(f32x4*)(out + obase + c * 4) = o;
    }
}

// ---------------------------------------------------------------------------
extern "C" void kernel_launch(void* const* d_in, const int* in_sizes, int n_in,
                              void* d_out, int out_size, void* d_ws, size_t ws_size,
                              hipStream_t stream)
{
    const float* ref_img = (const float*)d_in[0];
    const float* hdmap   = (const float*)d_in[1];
    const float* w_q     = (const float*)d_in[2];
    const float* w_k     = (const float*)d_in[3];
    const float* w_v     = (const float*)d_in[4];
    const float* w_o     = (const float*)d_in[5];
    const float* gamma   = (const float*)d_in[6];
    const float* beta    = (const float*)d_in[7];

    char* ws = (char*)d_ws;
    const size_t MB = 1024 * 1024;
    unsigned short* x  = (unsigned short*)(ws);              // [0,64M)
    unsigned short* q  = (unsigned short*)(ws + 64 * MB);    // [64,80M)  (also z2)
    unsigned short* k  = (unsigned short*)(ws + 80 * MB);    // [80,96M)
    unsigned short* v  = (unsigned short*)(ws + 96 * MB);    // [96,112M)
    float* sc          = (float*)(ws + 112 * MB);            // [112,144M) f32 [8][1024][1024]
    unsigned short* zo = (unsigned short*)(ws + 80 * MB);    // [80,144M) overlays k/v/sc
    float* stats       = (float*)(ws + 144 * MB);            // 32 B
    unsigned short* z2 = q;

    hipMemsetAsync(stats, 0, 32, stream);

    build_x_kernel<<<dim3(16, 1024), 256, 0, stream>>>(ref_img, hdmap, x);

    // QKV projections: bf16 x [4096,8192] @ f32 w [8192,2048] -> bf16
    gemm_kernel<0,1,0,0,0><<<dim3(16, 32, 1), 256, 0, stream>>>(
        x, w_q, q, nullptr, 4096, 2048, 8192, 8192, 2048, 2048,
        1, 0, 0, 0, 0, 0, 0, 1.0f);
    gemm_kernel<0,1,0,0,0><<<dim3(16, 32, 1), 256, 0, stream>>>(
        x, w_k, k, nullptr, 4096, 2048, 8192, 8192, 2048, 2048,
        1, 0, 0, 0, 0, 0, 0, 1.0f);
    gemm_kernel<0,1,0,0,0><<<dim3(16, 32, 1), 256, 0, stream>>>(
        x, w_v, v, nullptr, 4096, 2048, 8192, 8192, 2048, 2048,
        1, 0, 0, 0, 0, 0, 0, 1.0f);

    // Attention, batch-sequential (sc = 32 MiB).
    for (int b = 0; b < 4; ++b) {
        long o2 = (long)b * 2097152;   // per-batch offset in q/k/v/z2 (elements)
        // sc[h] = (1/16) Q_bh @ K_bh^T  (bf16 NT, f32 out), z = head
        gemm_kernel<0,0,1,1,0><<<dim3(8, 8, 8), 256, 0, stream>>>(
            (const void*)(q + o2), (const void*)(k + o2), sc, nullptr,
            1024, 1024, 256, 2048, 2048, 1024,
            8, 0, 256L, 0, 256L, 0, 1048576L, 0.0625f);
        softmax_kernel<<<8192, 256, 0, stream>>>(sc);
        // z2[b,h] = attn (f32 A) @ V_bh (bf16 NN) -> bf16
        gemm_kernel<1,0,0,0,0><<<dim3(2, 8, 8), 256, 0, stream>>>(
            sc, (const void*)(v + o2), (void*)(z2 + o2), nullptr,
            1024, 256, 1024, 1024, 2048, 2048,
            8, 0, 1048576L, 0, 256L, 0, 256L, 1.0f);
    }

    // zo = z2 @ w_o (f32 NN) + residual(x) -> bf16 (overlays dead k/v/sc)
    gemm_kernel<0,1,0,0,1><<<dim3(64, 32, 1), 256, 0, stream>>>(
        z2, w_o, zo, x, 4096, 8192, 2048, 2048, 8192, 8192,
        1, 0, 0, 0, 0, 0, 0, 1.0f);

    ln_stats_kernel<<<dim3(128, 4), 256, 0, stream>>>(zo, stats);
    ln_apply_kernel<<<dim3(128, 16, 4), 256, 0, stream>>>(
        zo, gamma, beta, stats, (float*)d_out);
}